// Round 7
// baseline (61.630 us; speedup 1.0000x reference)
//
#include <hip/hip_runtime.h>

// YOLOv1 loss: pred (N,7,7,30) fp32, target (N,7,7,25) fp32 -> scalar fp32.
// Round 7: round-4 structure (best: 33.4 us; wave-private LDS staging,
// T14 register prefetch, 4 waves/block, no barriers in hot loop) + FUSED
// final reduction (last-block-out, deterministic fixed-order sum) to remove
// the second kernel launch. Counter in d_ws zeroed per call via
// hipMemsetAsync (graph-capturable). Rounds 4-6 showed the kernel is
// insensitive to wave count / pipeline depth => at ~5.3 TB/s effective the
// remaining gap to the ~6.3 TB/s streaming ceiling is mostly fixed overhead.

#define NCLS 20
#define PRED_C 30
#define TGT_C  25
#define WCELLS 64                         // cells per wave-chunk
#define PRED_FL (WCELLS * PRED_C)         // 1920 floats = 7680 B
#define TGT_FL  (WCELLS * TGT_C)          // 1600 floats = 6400 B
#define SLICE_FL (PRED_FL + TGT_FL)       // 3520 floats = 14080 B per wave

__device__ __forceinline__ float block_reduce(float acc) {
    #pragma unroll
    for (int off = 32; off; off >>= 1) acc += __shfl_down(acc, off, 64);
    __shared__ float smem[4];
    int lane = threadIdx.x & 63, wid = threadIdx.x >> 6;
    if (lane == 0) smem[wid] = acc;
    __syncthreads();
    float s = 0.f;
    if (threadIdx.x == 0) {
        #pragma unroll
        for (int w = 0; w < 4; ++w) s += smem[w];
    }
    return s;
}

// Per-cell loss (pointers into LDS or global; inlined).
__device__ __forceinline__ float cell_loss(const float* __restrict__ pv,
                                           const float* __restrict__ tv) {
    const float LC = 5.0f;
    const float LN = 0.5f;
    const float EPS = 1e-6f;
    const float SQE = 1e-12f;

    float obj = tv[NCLS];

    float cls = 0.f;
    #pragma unroll
    for (int c = 0; c < NCLS; ++c) {
        float d = pv[c] - tv[c];
        cls += d * d;
    }

    float tx = tv[NCLS + 1], ty = tv[NCLS + 2];
    float tw = tv[NCLS + 3], th = tv[NCLS + 4];
    float bx1 = tx - tw * 0.5f, bx2 = tx + tw * 0.5f;
    float by1 = ty - th * 0.5f, by2 = ty + th * 0.5f;
    float tarea = tw * th;

    float c0 = pv[NCLS + 0];
    float x0 = pv[NCLS + 1], y0 = pv[NCLS + 2];
    float w0 = pv[NCLS + 3], h0 = pv[NCLS + 4];
    float a0x1 = x0 - w0 * 0.5f, a0x2 = x0 + w0 * 0.5f;
    float a0y1 = y0 - h0 * 0.5f, a0y2 = y0 + h0 * 0.5f;
    float iw0 = fmaxf(fminf(a0x2, bx2) - fmaxf(a0x1, bx1), 0.f);
    float ih0 = fmaxf(fminf(a0y2, by2) - fmaxf(a0y1, by1), 0.f);
    float in0 = iw0 * ih0;
    float iou0 = in0 / (w0 * h0 + tarea - in0 + EPS);

    float c1 = pv[NCLS + 5];
    float x1 = pv[NCLS + 6], y1 = pv[NCLS + 7];
    float w1 = pv[NCLS + 8], h1 = pv[NCLS + 9];
    float a1x1 = x1 - w1 * 0.5f, a1x2 = x1 + w1 * 0.5f;
    float a1y1 = y1 - h1 * 0.5f, a1y2 = y1 + h1 * 0.5f;
    float iw1 = fmaxf(fminf(a1x2, bx2) - fmaxf(a1x1, bx1), 0.f);
    float ih1 = fmaxf(fminf(a1y2, by2) - fmaxf(a1y1, by1), 0.f);
    float in1 = iw1 * ih1;
    float iou1 = in1 / (w1 * h1 + tarea - in1 + EPS);

    bool b0 = (iou0 >= iou1);               // first index wins ties (jnp.argmax)
    float best_iou = fmaxf(iou0, iou1);
    float bx = b0 ? x0 : x1;
    float by = b0 ? y0 : y1;
    float bw = b0 ? w0 : w1;
    float bh = b0 ? h0 : h1;
    float bc = b0 ? c0 : c1;

    float dx = bx - tx, dy = by - ty;
    float dw = sqrtf(fmaxf(bw, SQE)) - sqrtf(fmaxf(tw, SQE));
    float dh = sqrtf(fmaxf(bh, SQE)) - sqrtf(fmaxf(th, SQE));
    float coord = LC * (dx * dx + dy * dy + dw * dw + dh * dh);

    float dconf = bc - best_iou;
    float objconf = dconf * dconf;
    float noobj = LN * (c0 * c0 + c1 * c1);

    return obj * (cls + coord + objconf) + (1.f - obj) * noobj;
}

__global__ void __launch_bounds__(256)
yolo_loss_fused(const float* __restrict__ pred,
                const float* __restrict__ target,
                unsigned* __restrict__ counter,   // ws[0], zeroed per call
                float* __restrict__ partials,     // ws + 64B
                float* __restrict__ out,
                int nchunks, int ncells, float inv_n) {
    __shared__ float lds[4 * SLICE_FL];     // 56320 B -> 2 blocks/CU
    const int lane = threadIdx.x & 63;
    const int wid = threadIdx.x >> 6;
    float* wP = lds + wid * SLICE_FL;       // 1920 floats (pred chunk)
    float* wT = wP + PRED_FL;               // 1600 floats (target chunk)

    const int GW = gridDim.x * 4;           // total waves
    const int gw0 = blockIdx.x * 4 + wid;

    float acc = 0.f;

    // prefetch registers (statically named -> no scratch)
    float4 pr0, pr1, pr2, pr3, pr4, pr5, pr6; float2 prT;
    float4 tr0, tr1, tr2, tr3, tr4, tr5;      float  trT;

    auto loadRegs = [&](int c) {
        // pred chunk: 7680 B coalesced: 7 float4 rounds + 512B float2 round
        const float4* P4 = reinterpret_cast<const float4*>(pred)
                           + (size_t)c * (PRED_FL / 4) + lane;
        pr0 = P4[0 * 64]; pr1 = P4[1 * 64]; pr2 = P4[2 * 64]; pr3 = P4[3 * 64];
        pr4 = P4[4 * 64]; pr5 = P4[5 * 64]; pr6 = P4[6 * 64];
        prT = *(reinterpret_cast<const float2*>(pred)
                + (size_t)c * (PRED_FL / 2) + 896 + lane);
        // target chunk: 6400 B: 6 float4 rounds + 256B scalar round
        const float4* T4 = reinterpret_cast<const float4*>(target)
                           + (size_t)c * (TGT_FL / 4) + lane;
        tr0 = T4[0 * 64]; tr1 = T4[1 * 64]; tr2 = T4[2 * 64];
        tr3 = T4[3 * 64]; tr4 = T4[4 * 64]; tr5 = T4[5 * 64];
        trT = target[(size_t)c * TGT_FL + 1536 + lane];
    };
    auto writeLDS = [&]() {
        float4* p4 = reinterpret_cast<float4*>(wP);
        p4[0 * 64 + lane] = pr0; p4[1 * 64 + lane] = pr1;
        p4[2 * 64 + lane] = pr2; p4[3 * 64 + lane] = pr3;
        p4[4 * 64 + lane] = pr4; p4[5 * 64 + lane] = pr5;
        p4[6 * 64 + lane] = pr6;
        reinterpret_cast<float2*>(wP)[896 + lane] = prT;
        float4* t4 = reinterpret_cast<float4*>(wT);
        t4[0 * 64 + lane] = tr0; t4[1 * 64 + lane] = tr1;
        t4[2 * 64 + lane] = tr2; t4[3 * 64 + lane] = tr3;
        t4[4 * 64 + lane] = tr4; t4[5 * 64 + lane] = tr5;
        wT[1536 + lane] = trT;
    };

    int c = gw0;
    if (c < nchunks) {
        loadRegs(c);                 // prologue
        while (true) {
            writeLDS();              // regs(chunk c) -> LDS (waits vmcnt)
            int cn = c + GW;
            bool more = (cn < nchunks);
            if (more) loadRegs(cn);  // issue next chunk's loads EARLY (T14)
            acc += cell_loss(wP + lane * PRED_C, wT + lane * TGT_C);
            if (!more) break;
            c = cn;
        }
    }

    // generic tail (ncells % 64 != 0): direct global reads (not hit at N=16384)
    for (int cell = nchunks * WCELLS + blockIdx.x * 256 + threadIdx.x;
         cell < ncells; cell += gridDim.x * 256) {
        acc += cell_loss(pred + (size_t)cell * PRED_C,
                         target + (size_t)cell * TGT_C);
    }

    // ---- block partial + fused last-block final reduction ----
    float s = block_reduce(acc);
    __shared__ int sLast;
    if (threadIdx.x == 0) {
        __hip_atomic_store(&partials[blockIdx.x], s * inv_n,
                           __ATOMIC_RELEASE, __HIP_MEMORY_SCOPE_AGENT);
        unsigned old = __hip_atomic_fetch_add(counter, 1u,
                                              __ATOMIC_ACQ_REL,
                                              __HIP_MEMORY_SCOPE_AGENT);
        sLast = (old == (unsigned)(gridDim.x - 1));
    }
    __syncthreads();                 // broadcast sLast (also fences smem reuse)
    if (sLast) {
        // deterministic: fixed index order + fixed reduce tree, regardless of
        // which block finishes last
        float a = 0.f;
        for (int i = threadIdx.x; i < (int)gridDim.x; i += 256)
            a += __hip_atomic_load(&partials[i], __ATOMIC_RELAXED,
                                   __HIP_MEMORY_SCOPE_AGENT);
        float t = block_reduce(a);
        if (threadIdx.x == 0) out[0] = t;
    }
}

extern "C" void kernel_launch(void* const* d_in, const int* in_sizes, int n_in,
                              void* d_out, int out_size, void* d_ws, size_t ws_size,
                              hipStream_t stream) {
    const float* pred = (const float*)d_in[0];
    const float* target = (const float*)d_in[1];
    float* out = (float*)d_out;

    unsigned* counter = (unsigned*)d_ws;
    float* partials = (float*)((char*)d_ws + 64);

    int N = in_sizes[0] / (7 * 7 * PRED_C);
    int ncells = N * 7 * 7;                 // 802816
    int nchunks = ncells / WCELLS;          // 12544 (exact for N=16384)

    int nblk = 512;                          // 2 blocks/CU x 256 CU
    int wsCap = (int)((ws_size - 64) / sizeof(float));
    if (nblk > wsCap) nblk = wsCap;
    if (nblk < 1) nblk = 1;

    hipMemsetAsync(d_ws, 0, 64, stream);    // zero the arrival counter
    yolo_loss_fused<<<nblk, 256, 0, stream>>>(pred, target, counter, partials,
                                              out, nchunks, ncells,
                                              1.0f / (float)N);
}

// Round 8
// 35.403 us; speedup vs baseline: 1.7408x; 1.7408x over previous
//
#include <hip/hip_runtime.h>

// YOLOv1 loss: pred (N,7,7,30) fp32, target (N,7,7,25) fp32 -> scalar fp32.
// Round 8: REVERT to round-4 structure (best: 33.4 us) — wave-private LDS
// staging, 1-deep register prefetch (T14), 4 waves/block, no barriers in the
// hot loop — plus two micro-fixes:
//   (1) contiguous per-wave chunk runs (DRAM/L3 page locality) instead of
//       stride-GW hopping;
//   (2) per-wave partials (pure shuffle reduce, no __syncthreads epilogue);
//       tiny second kernel sums them in fixed order (deterministic).
// Round 7's fused last-block-out reduction regressed 2x (agent-scope acq/rel
// atomics poisoned the dispatch) — two-kernel split restored.
// Evidence says we sit at an L2-miss latency x concurrency wall (~5.3 TB/s
// effective): request-count varies 15x across rounds 1/4 with only 10% time
// delta; warm L3-resident replays are no faster than cold; three different
// pipeline structures tie.

#define NCLS 20
#define PRED_C 30
#define TGT_C  25
#define WCELLS 64                         // cells per wave-chunk
#define PRED_FL (WCELLS * PRED_C)         // 1920 floats = 7680 B
#define TGT_FL  (WCELLS * TGT_C)          // 1600 floats = 6400 B
#define SLICE_FL (PRED_FL + TGT_FL)       // 3520 floats = 14080 B per wave

// Per-cell loss (pointers into LDS or global; inlined).
__device__ __forceinline__ float cell_loss(const float* __restrict__ pv,
                                           const float* __restrict__ tv) {
    const float LC = 5.0f;
    const float LN = 0.5f;
    const float EPS = 1e-6f;
    const float SQE = 1e-12f;

    float obj = tv[NCLS];

    float cls = 0.f;
    #pragma unroll
    for (int c = 0; c < NCLS; ++c) {
        float d = pv[c] - tv[c];
        cls += d * d;
    }

    float tx = tv[NCLS + 1], ty = tv[NCLS + 2];
    float tw = tv[NCLS + 3], th = tv[NCLS + 4];
    float bx1 = tx - tw * 0.5f, bx2 = tx + tw * 0.5f;
    float by1 = ty - th * 0.5f, by2 = ty + th * 0.5f;
    float tarea = tw * th;

    float c0 = pv[NCLS + 0];
    float x0 = pv[NCLS + 1], y0 = pv[NCLS + 2];
    float w0 = pv[NCLS + 3], h0 = pv[NCLS + 4];
    float a0x1 = x0 - w0 * 0.5f, a0x2 = x0 + w0 * 0.5f;
    float a0y1 = y0 - h0 * 0.5f, a0y2 = y0 + h0 * 0.5f;
    float iw0 = fmaxf(fminf(a0x2, bx2) - fmaxf(a0x1, bx1), 0.f);
    float ih0 = fmaxf(fminf(a0y2, by2) - fmaxf(a0y1, by1), 0.f);
    float in0 = iw0 * ih0;
    float iou0 = in0 / (w0 * h0 + tarea - in0 + EPS);

    float c1 = pv[NCLS + 5];
    float x1 = pv[NCLS + 6], y1 = pv[NCLS + 7];
    float w1 = pv[NCLS + 8], h1 = pv[NCLS + 9];
    float a1x1 = x1 - w1 * 0.5f, a1x2 = x1 + w1 * 0.5f;
    float a1y1 = y1 - h1 * 0.5f, a1y2 = y1 + h1 * 0.5f;
    float iw1 = fmaxf(fminf(a1x2, bx2) - fmaxf(a1x1, bx1), 0.f);
    float ih1 = fmaxf(fminf(a1y2, by2) - fmaxf(a1y1, by1), 0.f);
    float in1 = iw1 * ih1;
    float iou1 = in1 / (w1 * h1 + tarea - in1 + EPS);

    bool b0 = (iou0 >= iou1);               // first index wins ties (jnp.argmax)
    float best_iou = fmaxf(iou0, iou1);
    float bx = b0 ? x0 : x1;
    float by = b0 ? y0 : y1;
    float bw = b0 ? w0 : w1;
    float bh = b0 ? h0 : h1;
    float bc = b0 ? c0 : c1;

    float dx = bx - tx, dy = by - ty;
    float dw = sqrtf(fmaxf(bw, SQE)) - sqrtf(fmaxf(tw, SQE));
    float dh = sqrtf(fmaxf(bh, SQE)) - sqrtf(fmaxf(th, SQE));
    float coord = LC * (dx * dx + dy * dy + dw * dw + dh * dh);

    float dconf = bc - best_iou;
    float objconf = dconf * dconf;
    float noobj = LN * (c0 * c0 + c1 * c1);

    return obj * (cls + coord + objconf) + (1.f - obj) * noobj;
}

__global__ void __launch_bounds__(256)
yolo_loss_partial(const float* __restrict__ pred,
                  const float* __restrict__ target,
                  float* __restrict__ partials,   // one per wave
                  int nchunks, int ncells, float inv_n) {
    __shared__ float lds[4 * SLICE_FL];     // 56320 B -> 2 blocks/CU
    const int lane = threadIdx.x & 63;
    const int wid = threadIdx.x >> 6;
    float* wP = lds + wid * SLICE_FL;       // 1920 floats (pred chunk)
    float* wT = wP + PRED_FL;               // 1600 floats (target chunk)

    const int GW = gridDim.x * 4;           // total waves
    const int gw = blockIdx.x * 4 + wid;

    // contiguous run of chunks for this wave: [s, e)
    const int s = (int)(((long)gw * nchunks) / GW);
    const int e = (int)(((long)(gw + 1) * nchunks) / GW);

    float acc = 0.f;

    // prefetch registers (statically named -> no scratch)
    float4 pr0, pr1, pr2, pr3, pr4, pr5, pr6; float2 prT;
    float4 tr0, tr1, tr2, tr3, tr4, tr5;      float  trT;

    auto loadRegs = [&](int c) {
        // pred chunk: 7680 B coalesced: 7 float4 rounds + 512B float2 round
        const float4* P4 = reinterpret_cast<const float4*>(pred)
                           + (size_t)c * (PRED_FL / 4) + lane;
        pr0 = P4[0 * 64]; pr1 = P4[1 * 64]; pr2 = P4[2 * 64]; pr3 = P4[3 * 64];
        pr4 = P4[4 * 64]; pr5 = P4[5 * 64]; pr6 = P4[6 * 64];
        prT = *(reinterpret_cast<const float2*>(pred)
                + (size_t)c * (PRED_FL / 2) + 896 + lane);
        // target chunk: 6400 B: 6 float4 rounds + 256B scalar round
        const float4* T4 = reinterpret_cast<const float4*>(target)
                           + (size_t)c * (TGT_FL / 4) + lane;
        tr0 = T4[0 * 64]; tr1 = T4[1 * 64]; tr2 = T4[2 * 64];
        tr3 = T4[3 * 64]; tr4 = T4[4 * 64]; tr5 = T4[5 * 64];
        trT = target[(size_t)c * TGT_FL + 1536 + lane];
    };
    auto writeLDS = [&]() {
        float4* p4 = reinterpret_cast<float4*>(wP);
        p4[0 * 64 + lane] = pr0; p4[1 * 64 + lane] = pr1;
        p4[2 * 64 + lane] = pr2; p4[3 * 64 + lane] = pr3;
        p4[4 * 64 + lane] = pr4; p4[5 * 64 + lane] = pr5;
        p4[6 * 64 + lane] = pr6;
        reinterpret_cast<float2*>(wP)[896 + lane] = prT;
        float4* t4 = reinterpret_cast<float4*>(wT);
        t4[0 * 64 + lane] = tr0; t4[1 * 64 + lane] = tr1;
        t4[2 * 64 + lane] = tr2; t4[3 * 64 + lane] = tr3;
        t4[4 * 64 + lane] = tr4; t4[5 * 64 + lane] = tr5;
        wT[1536 + lane] = trT;
    };

    if (s < e) {
        loadRegs(s);                 // prologue
        for (int c = s; c < e; ++c) {
            writeLDS();              // regs(chunk c) -> LDS (waits vmcnt)
            if (c + 1 < e) loadRegs(c + 1);   // issue next loads EARLY (T14)
            // compute cell `lane` of chunk c from LDS; loads fly underneath
            acc += cell_loss(wP + lane * PRED_C, wT + lane * TGT_C);
        }
    }

    // generic tail (ncells % 64 != 0): direct global reads (not hit at N=16384)
    for (int cell = nchunks * WCELLS + blockIdx.x * 256 + threadIdx.x;
         cell < ncells; cell += gridDim.x * 256) {
        acc += cell_loss(pred + (size_t)cell * PRED_C,
                         target + (size_t)cell * TGT_C);
    }

    // per-wave partial: pure shuffle reduce, no barriers
    #pragma unroll
    for (int off = 32; off; off >>= 1) acc += __shfl_down(acc, off, 64);
    if (lane == 0) partials[gw] = acc * inv_n;
}

__global__ void __launch_bounds__(256)
yolo_reduce(const float* __restrict__ partials, float* __restrict__ out, int n) {
    // fixed index order + fixed reduce tree -> deterministic
    float acc = 0.f;
    for (int i = threadIdx.x; i < n; i += blockDim.x) acc += partials[i];
    #pragma unroll
    for (int off = 32; off; off >>= 1) acc += __shfl_down(acc, off, 64);
    __shared__ float smem[4];
    int lane = threadIdx.x & 63, wid = threadIdx.x >> 6;
    if (lane == 0) smem[wid] = acc;
    __syncthreads();
    if (threadIdx.x == 0) {
        float s = 0.f;
        #pragma unroll
        for (int w = 0; w < 4; ++w) s += smem[w];
        out[0] = s;
    }
}

extern "C" void kernel_launch(void* const* d_in, const int* in_sizes, int n_in,
                              void* d_out, int out_size, void* d_ws, size_t ws_size,
                              hipStream_t stream) {
    const float* pred = (const float*)d_in[0];
    const float* target = (const float*)d_in[1];
    float* out = (float*)d_out;
    float* partials = (float*)d_ws;

    int N = in_sizes[0] / (7 * 7 * PRED_C);
    int ncells = N * 7 * 7;                 // 802816
    int nchunks = ncells / WCELLS;          // 12544 (exact for N=16384)

    int nblk = 512;                          // 2 blocks/CU x 256 CU
    int wsCap = (int)(ws_size / sizeof(float)) / 4;
    if (nblk > wsCap) nblk = wsCap;
    if (nblk < 1) nblk = 1;
    int nwaves = nblk * 4;

    yolo_loss_partial<<<nblk, 256, 0, stream>>>(pred, target, partials,
                                                nchunks, ncells,
                                                1.0f / (float)N);
    yolo_reduce<<<1, 256, 0, stream>>>(partials, out, nwaves);
}